// Round 10
// baseline (451.681 us; speedup 1.0000x reference)
//
#include <hip/hip_runtime.h>
#include <cstdint>
#include <cstddef>

#define E_DIM   1024
#define NHEADS  16
#define DHEAD   64
#define BATCH   8
#define SEQ     1024
#define MROWS   (BATCH*SEQ)   // 8192

#define LOG2E 1.44269504f

typedef __bf16 bf16;
typedef __attribute__((ext_vector_type(8))) __bf16 bf16x8;
typedef __attribute__((ext_vector_type(4))) __bf16 bf16x4;
typedef __attribute__((ext_vector_type(4))) float f32x4;

typedef const __attribute__((address_space(1))) unsigned int gu32;
typedef __attribute__((address_space(3))) unsigned int lu32;

// ---------------------------------------------------------------------------
// split fp32 -> bf16 hi + bf16 lo  (weights only)
// ---------------------------------------------------------------------------
__global__ __launch_bounds__(256)
void split_kernel(const float* __restrict__ src, bf16* __restrict__ hi,
                  bf16* __restrict__ lo, int n4)
{
    int i = blockIdx.x * 256 + threadIdx.x;
    if (i >= n4) return;
    float4 x = ((const float4*)src)[i];
    bf16x4 h, l;
    h[0] = (bf16)x.x; l[0] = (bf16)(x.x - (float)h[0]);
    h[1] = (bf16)x.y; l[1] = (bf16)(x.y - (float)h[1]);
    h[2] = (bf16)x.z; l[2] = (bf16)(x.z - (float)h[2]);
    h[3] = (bf16)x.w; l[3] = (bf16)(x.w - (float)h[3]);
    ((bf16x4*)hi)[i] = h;
    ((bf16x4*)lo)[i] = l;
}

// fp32 -> bf16 with scale (mask pre-scaled by log2e for exp2-domain softmax)
__global__ __launch_bounds__(256)
void cvt_bf16_kernel(const float* __restrict__ src, bf16* __restrict__ dst,
                     float scale, int n4)
{
    int i = blockIdx.x * 256 + threadIdx.x;
    if (i >= n4) return;
    float4 x = ((const float4*)src)[i];
    bf16x4 h;
    h[0] = (bf16)(x.x * scale); h[1] = (bf16)(x.y * scale);
    h[2] = (bf16)(x.z * scale); h[3] = (bf16)(x.w * scale);
    ((bf16x4*)dst)[i] = h;
}

// ---------------------------------------------------------------------------
// MFMA GEMM, split-bf16 3-term K-loop: acc += Ahi.Whi + Ahi.Wlo + Alo.Whi
// 64x64-wave-tile experiment, SAFE SYNC VARIANT: no inline asm, no raw
// barriers. Per iter: {__syncthreads (drains stage(cur), fences buffer reuse)
// -> ds_read frags(cur) -> issue stage(cur^1) -> MFMA}. Distance-1 prefetch
// overlap identical to the counted-vmcnt version at this pipeline depth;
// compiler inserts all waitcnts.
// 256 thr / 4 waves, wave tile 64x64 (acc[4][4]), BM=BN=128, LDS 64KB dbuf
// -> 2 blocks/CU. LDS frag reads 96->64 KB per block-iter vs 32x64 tiles.
// AMODE=1: A staged fp32, hi/lo derived in-reg. AMODE=0: A pre-split bf16.
// ---------------------------------------------------------------------------
template<int AMODE>
__global__ __launch_bounds__(256, 2)
void gemm_nt_mfma(const float* __restrict__ Af0, const float* __restrict__ Af1,
                  const float* __restrict__ Af2,
                  const bf16* __restrict__ Ahi, const bf16* __restrict__ Alo,
                  const bf16* __restrict__ Whi, const bf16* __restrict__ Wlo,
                  const float* __restrict__ bias,
                  float* __restrict__ outF, bf16* __restrict__ outHi,
                  int M, int N, int K)
{
    // A buffer: 16KB/stage = 128x32 fp32  OR  2 x (128x32 bf16) hi+lo
    __shared__ char  smemA[2][16384];
    __shared__ bf16  Whs[2][128 * 32];
    __shared__ bf16  Wls[2][128 * 32];

    const int tid  = threadIdx.x;       // 0..255
    const int lane = tid & 63;
    const int wid  = tid >> 6;          // 0..3
    const int wm = (wid >> 1) * 64;     // 2 row-groups of 64
    const int wn = (wid & 1) * 64;      // 2 col-groups of 64
    const int fr = lane & 15;
    const int fq = lane >> 4;                       // logical k-slot (8 elems)
    const int fk = ((fq + (fr >> 1)) & 3) * 8;      // W phys slot (per-lane const)

    // fused-z selection
    const int z = blockIdx.y;
    const float* Af = (z == 0) ? Af0 : (z == 1) ? Af1 : Af2;
    const bf16* Wh = Whi + (size_t)z * E_DIM * E_DIM;
    const bf16* Wl = Wlo + (size_t)z * E_DIM * E_DIM;
    const float* bs = bias + z * E_DIM;
    const int mode = AMODE ? ((z == 2) ? 2 : 1) : 0;

    // concurrency-aware XCD swizzle (bijective on id<512):
    const int id = blockIdx.x;
    const int mTile = (id & 7) + 8 * (id >> 6);   // 0..63
    const int nTile = (id >> 3) & 7;              // 0..7
    const int mBase = mTile * 128;
    const int nBase = nTile * 128;

    // --- staging geometry (256 threads) ---
    // W (bf16): 4 lanes/row (64B rows), 2 instrs of 64 rows, rotated slot
    const int rowW  = tid >> 2;                                 // 0..63
    const int colW  = (((tid & 3) - ((tid >> 3) & 3)) & 3) * 8;
    // A fp32: 8 lanes/row (128B rows), 4 instrs of 32 rows, rotated slot
    const int rowAf  = tid >> 3;                                // 0..31
    const int slotAf = ((tid & 7) - (rowAf & 7)) & 7;

    const int dcol = lane & 15;
    float bv[4];
#pragma unroll
    for (int bn = 0; bn < 4; ++bn)
        bv[bn] = bs[nBase + wn + bn * 16 + dcol];

    f32x4 acc[4][4];
#pragma unroll
    for (int i = 0; i < 4; ++i)
#pragma unroll
        for (int j = 0; j < 4; ++j) acc[i][j] = (f32x4){0.f, 0.f, 0.f, 0.f};

    // loop-carried staging pointers (advance 32 elems per k-step)
    const float* pAf = Af  + (size_t)(mBase + rowAf) * K + slotAf * 4;
    const bf16*  pAh = Ahi + (size_t)(mBase + rowW) * K + colW;
    const bf16*  pAl = Alo + (size_t)(mBase + rowW) * K + colW;
    const bf16*  pWh = Wh  + (size_t)(nBase + rowW) * K + colW;
    const bf16*  pWl = Wl  + (size_t)(nBase + rowW) * K + colW;

    auto stage = [&](int bi) {
        if (AMODE == 1) {
            float* As = (float*)smemA[bi];
#pragma unroll
            for (int i = 0; i < 4; ++i)
                __builtin_amdgcn_global_load_lds((gu32*)(pAf + (size_t)(i * 32) * K),
                                                 (lu32*)&As[i * 1024 + wid * 256], 16, 0, 0);
            pAf += 32;
        } else {
            bf16* Ah = (bf16*)smemA[bi];
            bf16* Al = Ah + 4096;
#pragma unroll
            for (int j = 0; j < 2; ++j) {
                __builtin_amdgcn_global_load_lds((gu32*)(pAh + (size_t)(j * 64) * K),
                                                 (lu32*)&Ah[j * 2048 + wid * 512], 16, 0, 0);
                __builtin_amdgcn_global_load_lds((gu32*)(pAl + (size_t)(j * 64) * K),
                                                 (lu32*)&Al[j * 2048 + wid * 512], 16, 0, 0);
            }
            pAh += 32; pAl += 32;
        }
#pragma unroll
        for (int j = 0; j < 2; ++j) {
            __builtin_amdgcn_global_load_lds((gu32*)(pWh + (size_t)(j * 64) * K),
                                             (lu32*)&Whs[bi][j * 2048 + wid * 512], 16, 0, 0);
            __builtin_amdgcn_global_load_lds((gu32*)(pWl + (size_t)(j * 64) * K),
                                             (lu32*)&Wls[bi][j * 2048 + wid * 512], 16, 0, 0);
        }
        pWh += 32; pWl += 32;
    };

    stage(0);

    const int NIT = K >> 5;
#pragma unroll 1
    for (int it = 0; it < NIT; ++it) {
        const int cur = it & 1;
        // Drains this wave's outstanding stage loads (vmcnt 0) + barrier:
        // buf[cur] is fully staged for ALL waves, and all waves are done
        // reading buf[cur^1] -> safe to overwrite it below.
        __syncthreads();

        bf16x8 afh[4], afl[4], bfh[4], bfl[4];
        if (AMODE == 1) {
            const float* As = (const float*)smemA[cur];
#pragma unroll
            for (int am = 0; am < 4; ++am) {
                const int row = wm + am * 16 + fr;
                const float* Ar = &As[row * 32];
                f32x4 a0 = *(const f32x4*)&Ar[((2 * fq     + (fr & 7)) & 7) * 4];
                f32x4 a1 = *(const f32x4*)&Ar[((2 * fq + 1 + (fr & 7)) & 7) * 4];
                bf16x8 h, l;
#pragma unroll
                for (int j = 0; j < 4; ++j) {
                    h[j]     = (bf16)a0[j];
                    l[j]     = (bf16)(a0[j] - (float)h[j]);
                    h[j + 4] = (bf16)a1[j];
                    l[j + 4] = (bf16)(a1[j] - (float)h[j + 4]);
                }
                afh[am] = h; afl[am] = l;
            }
        } else {
            const bf16* Ah = (const bf16*)smemA[cur];
            const bf16* Al = Ah + 4096;
#pragma unroll
            for (int am = 0; am < 4; ++am) {
                afh[am] = *(const bf16x8*)&Ah[(wm + am * 16 + fr) * 32 + fk];
                afl[am] = *(const bf16x8*)&Al[(wm + am * 16 + fr) * 32 + fk];
            }
        }
#pragma unroll
        for (int bn = 0; bn < 4; ++bn) {
            bfh[bn] = *(const bf16x8*)&Whs[cur][(wn + bn * 16 + fr) * 32 + fk];
            bfl[bn] = *(const bf16x8*)&Wls[cur][(wn + bn * 16 + fr) * 32 + fk];
        }

        // prefetch next tile into buf[cur^1]; its HBM latency hides under the
        // MFMA phase; the NEXT iteration's __syncthreads drains it.
        if (it + 1 < NIT) stage(cur ^ 1);

        __builtin_amdgcn_s_setprio(1);
#pragma unroll
        for (int am = 0; am < 4; ++am)
#pragma unroll
            for (int bn = 0; bn < 4; ++bn) {
                acc[am][bn] = __builtin_amdgcn_mfma_f32_16x16x32_bf16(afh[am], bfh[bn], acc[am][bn], 0, 0, 0);
                acc[am][bn] = __builtin_amdgcn_mfma_f32_16x16x32_bf16(afh[am], bfl[bn], acc[am][bn], 0, 0, 0);
                acc[am][bn] = __builtin_amdgcn_mfma_f32_16x16x32_bf16(afl[am], bfh[bn], acc[am][bn], 0, 0, 0);
            }
        __builtin_amdgcn_s_setprio(0);
    }

    const int drow = (lane >> 4) * 4;
#pragma unroll
    for (int bn = 0; bn < 4; ++bn) {
        const int col = nBase + wn + bn * 16 + dcol;
#pragma unroll
        for (int am = 0; am < 4; ++am) {
#pragma unroll
            for (int r = 0; r < 4; ++r) {
                const int row = mBase + wm + am * 16 + drow + r;
                const float v = acc[am][bn][r] + bv[bn];
                if (mode == 0) {
                    outF[(size_t)row * N + col] = v;
                } else {
                    const int b = row >> 10, t = row & 1023;
                    const int h = col >> 6,  d = col & 63;
                    size_t idx;
                    if (mode == 1)
                        idx = (((size_t)(b * NHEADS + h)) * SEQ + t) * DHEAD + d;
                    else
                        idx = (((size_t)(b * NHEADS + h)) * DHEAD + d) * SEQ + t;
                    outHi[(size_t)z * MROWS * E_DIM + idx] = (bf16)v;
                }
            }
        }
    }
}

// ---------------------------------------------------------------------------
// MFMA flash attention (unchanged — r7-verified)
// ---------------------------------------------------------------------------
__global__ __launch_bounds__(512)
void attn_mfma_kernel(const bf16* __restrict__ qkv,
                      const bf16* __restrict__ mask_bf,     // pre-scaled by log2e
                      const unsigned char* __restrict__ kpad,
                      bf16* __restrict__ ctx_hi, bf16* __restrict__ ctx_lo)
{
    __shared__ bf16 Ks [2][4096];               // 16 KB
    __shared__ bf16 Vts[2][4096];               // 16 KB
    __shared__ bf16 Pn[8][1024];                // 16 KB, XOR-swizzled, wave-private

    const int tid  = threadIdx.x;
    const int lane = tid & 63;
    const int wid  = tid >> 6;          // 0..7
    const int c16  = lane & 15;
    const int quad = lane >> 4;

    const int bh = blockIdx.x;             // 0..127
    const int qt = blockIdx.y;             // 0..7
    const int b = bh >> 4, h = bh & 15;

    const size_t seg = (size_t)MROWS * E_DIM;
    const size_t headoff = (size_t)bh * SEQ * DHEAD;
    const bf16* Q_g  = qkv + headoff;
    const bf16* K_g  = qkv + seg + headoff;
    const bf16* Vt_g = qkv + 2 * seg + headoff;   // [d][t]

    const int qglob = qt * 128 + wid * 16 + c16;

    bf16x8 qf[2];
#pragma unroll
    for (int ks = 0; ks < 2; ++ks)
        qf[ks] = *(const bf16x8*)&Q_g[(size_t)qglob * DHEAD + quad * 8 + ks * 32];

    float l_i = 0.f;
    f32x4 oacc[4];
#pragma unroll
    for (int dt = 0; dt < 4; ++dt) oacc[dt] = (f32x4){0.f, 0.f, 0.f, 0.f};

    const int row0 = tid >> 3;                       // 0..63
    const int c0   = (tid & 7) ^ (row0 & 7);

    auto stage = [&](int kt, int bi) {
        const int ktb = kt * 64;
        const size_t k0 = (size_t)(ktb + row0) * DHEAD + c0 * 8;
        const size_t v0 = (size_t)row0 * SEQ + ktb + c0 * 8;
        __builtin_amdgcn_global_load_lds((gu32*)(K_g + k0),  (lu32*)&Ks [bi][wid * 512], 16, 0, 0);
        __builtin_amdgcn_global_load_lds((gu32*)(Vt_g + v0), (lu32*)&Vts[bi][wid * 512], 16, 0, 0);
    };

    stage(0, 0);
    __syncthreads();

    const int pxor = (c16 & 7) << 3;
    const size_t kpb = (size_t)b * SEQ + quad * 4;

#pragma unroll 1
    for (int kt = 0; kt < 16; ++kt) {
        const int cur = kt & 1;
        const int ktb = kt * 64;

        bf16x4 mvh[4];
        unsigned kpu[4];
#pragma unroll
        for (int st = 0; st < 4; ++st) {
            mvh[st] = *(const bf16x4*)&mask_bf[(size_t)qglob * SEQ + ktb + st * 16 + quad * 4];
            kpu[st] = *(const unsigned*)&kpad[kpb + ktb + st * 16];
        }

        if (kt < 15) stage(kt + 1, cur ^ 1);

        // ---- S^T = K.Q^T ----
        f32x4 sacc[4];
#pragma unroll
        for (int st = 0; st < 4; ++st) sacc[st] = (f32x4){0.f, 0.f, 0.f, 0.f};
        __builtin_amdgcn_s_setprio(1);
#pragma unroll
        for (int st = 0; st < 4; ++st) {
            const int row = st * 16 + c16;
            const int sw  = row & 7;
#pragma unroll
            for (int ks = 0; ks < 2; ++ks) {
                const int cp = ((quad + ks * 4) ^ sw);
                bf16x8 kh = *(const bf16x8*)&Ks[cur][(row * 8 + cp) * 8];
                sacc[st] = __builtin_amdgcn_mfma_f32_16x16x32_bf16(kh, qf[ks], sacc[st], 0, 0, 0);
            }
        }
        __builtin_amdgcn_s_setprio(0);

        // ---- softmax numerator (fixed exp2 base; no max tracking) ----
        float s[16];
#pragma unroll
        for (int st = 0; st < 4; ++st) {
#pragma unroll
            for (int r = 0; r < 4; ++r)
                s[st * 4 + r] = fmaf(sacc[st][r], 0.125f * LOG2E, (float)mvh[st][r]);
        }
        if (__any((kpu[0] | kpu[1] | kpu[2] | kpu[3]) != 0u)) {
#pragma unroll
            for (int st = 0; st < 4; ++st)
#pragma unroll
                for (int r = 0; r < 4; ++r)
                    if ((kpu[st] >> (r * 8)) & 0xff) s[st * 4 + r] = -2e30f;
        }
        float p[16];
#pragma unroll
        for (int i = 0; i < 16; ++i)
            p[i] = __builtin_amdgcn_exp2f(fminf(s[i], 30.f));   // overflow guard
        float u8[8];
#pragma unroll
        for (int i = 0; i < 8; ++i) u8[i] = p[i] + p[i + 8];
#pragma unroll
        for (int i = 0; i < 4; ++i) u8[i] += u8[i + 4];
        float ps = (u8[0] + u8[1]) + (u8[2] + u8[3]);
        ps += __shfl_xor(ps, 16, 64);
        ps += __shfl_xor(ps, 32, 64);
        l_i += ps;

        // ---- P (bf16) via XOR-swizzled wave-private LDS ----
#pragma unroll
        for (int st = 0; st < 4; ++st) {
            bf16x4 ph;
#pragma unroll
            for (int r = 0; r < 4; ++r) ph[r] = (bf16)p[st * 4 + r];
            *(bf16x4*)&Pn[wid][c16 * 64 + ((st * 16 + quad * 4) ^ pxor)] = ph;
        }
        bf16x8 pf[2];
#pragma unroll
        for (int ks = 0; ks < 2; ++ks)
            pf[ks] = *(const bf16x8*)&Pn[wid][c16 * 64 + ((ks * 32 + quad * 8) ^ pxor)];

        // ---- O^T += V^T.P ----
        __builtin_amdgcn_s_setprio(1);
#pragma unroll
        for (int dt = 0; dt < 4; ++dt) {
            const int row = dt * 16 + c16;
            const int sw  = row & 7;
#pragma unroll
            for (int ks = 0; ks < 2; ++ks) {
                const int cp = ((quad + ks * 4) ^ sw);
                bf16x8 vh = *(const bf16x8*)&Vts[cur][(row * 8 + cp) * 8];
                oacc[dt] = __builtin_amdgcn_mfma_f32_16x16x32_bf16(vh, pf[ks], oacc[dt], 0, 0, 0);
            }
        }
        __builtin_amdgcn_s_setprio(0);

        __syncthreads();   // drains prefetch(kt+1); guards buffer reuse
    }

    // ---- epilogue: split O into hi/lo for the out-projection ----
    const float invl = 1.0f / l_i;
#pragma unroll
    for (int dt = 0; dt < 4; ++dt) {
        bf16x4 oh, ol;
#pragma unroll
        for (int r = 0; r < 4; ++r) {
            float v = oacc[dt][r] * invl;
            oh[r] = (bf16)v;
            ol[r] = (bf16)(v - (float)oh[r]);
        }
        size_t idx = ((size_t)b * SEQ + qglob) * E_DIM + h * DHEAD + dt * 16 + quad * 4;
        *(bf16x4*)&ctx_hi[idx] = oh;
        *(bf16x4*)&ctx_lo[idx] = ol;
    }
}

// ---------------------------------------------------------------------------
extern "C" void kernel_launch(void* const* d_in, const int* in_sizes, int n_in,
                              void* d_out, int out_size, void* d_ws, size_t ws_size,
                              hipStream_t stream)
{
    const float* q_in = (const float*)d_in[0];
    const float* k_in = (const float*)d_in[1];
    const float* v_in = (const float*)d_in[2];
    const unsigned char* kpad = (const unsigned char*)d_in[3];
    const float* attn_mask = (const float*)d_in[4];
    const float* w_in  = (const float*)d_in[5];
    const float* b_in  = (const float*)d_in[6];
    const float* w_out = (const float*)d_in[7];
    const float* b_out = (const float*)d_in[8];
    float* out = (float*)d_out;

    char* ws = (char*)d_ws;
    const size_t MB = 1024 * 1024;
    bf16* w_in_hi  = (bf16*)(ws + 0 * MB);    // 6MB
    bf16* w_in_lo  = (bf16*)(ws + 6 * MB);    // 6MB
    bf16* w_out_hi = (bf16*)(ws + 12 * MB);   // 2MB
    bf16* w_out_lo = (bf16*)(ws + 14 * MB);   // 2MB
    bf16* qkv      = (bf16*)(ws + 16 * MB);   // 48MB (Q,K,Vt bf16)
    bf16* mask_bf  = (bf16*)(ws + 64 * MB);   // 2MB
    bf16* ctx_hi   = (bf16*)(ws + 66 * MB);   // 16MB
    bf16* ctx_lo   = (bf16*)(ws + 82 * MB);   // 16MB

    split_kernel<<<(3 * E_DIM * E_DIM / 4 + 255) / 256, 256, 0, stream>>>(
        w_in, w_in_hi, w_in_lo, 3 * E_DIM * E_DIM / 4);
    split_kernel<<<(E_DIM * E_DIM / 4 + 255) / 256, 256, 0, stream>>>(
        w_out, w_out_hi, w_out_lo, E_DIM * E_DIM / 4);
    cvt_bf16_kernel<<<(SEQ * SEQ / 4 + 255) / 256, 256, 0, stream>>>(
        attn_mask, mask_bf, LOG2E, SEQ * SEQ / 4);

    // fused in-projection: one dispatch, z = {q,k,v}
    gemm_nt_mfma<1><<<dim3(512, 3), 256, 0, stream>>>(
        q_in, k_in, v_in,
        nullptr, nullptr,
        w_in_hi, w_in_lo, b_in,
        nullptr, qkv,
        MROWS, E_DIM, E_DIM);

    attn_mfma_kernel<<<dim3(BATCH * NHEADS, SEQ / 128), 512, 0, stream>>>(
        qkv, mask_bf, kpad, ctx_hi, ctx_lo);

    gemm_nt_mfma<0><<<dim3(512, 1), 256, 0, stream>>>(
        nullptr, nullptr, nullptr,
        ctx_hi, ctx_lo, w_out_hi, w_out_lo, b_out,
        out, nullptr,
        MROWS, E_DIM, E_DIM);
}